// Round 1
// baseline (302.251 us; speedup 1.0000x reference)
//
#include <hip/hip_runtime.h>

// VQ-VAE vector quantizer forward (fp32).
// inputs: (32,256,32,32) f32 -> flat rows N=32768 x D=256
// embedding: (D=256, K=1024) f32, cluster_size: (1024,) f32
// outputs (flat f32): quantized[N*D], vq_loss, perplexity, code_usage, indices[N] (as float)

constexpr int DIM = 256;   // embedding dim (rows of embedding)
constexpr int NK  = 1024;  // number of codes (cols of embedding)
constexpr int RR  = 16;    // input rows per block in argmin kernel

// ---------------------------------------------------------------- enorm
__global__ __launch_bounds__(256) void enorm_kernel(
    const float* __restrict__ emb, float* __restrict__ enorm) {
  int k = blockIdx.x * 256 + threadIdx.x;
  float s = 0.f;
  for (int d = 0; d < DIM; ++d) {
    float e = emb[(size_t)d * NK + k];   // coalesced across threads per d
    s = fmaf(e, e, s);
  }
  enorm[k] = s;
}

// ---------------------------------------------------------------- argmin
// Block: 256 threads, handles RR=16 input rows vs all 1024 codes.
// Thread t owns codes 4t..4t+3 (float4-coalesced embedding loads).
__global__ __launch_bounds__(256) void argmin_kernel(
    const float* __restrict__ x, const float* __restrict__ emb,
    const float* __restrict__ enorm, int* __restrict__ idx_out,
    float* __restrict__ idx_out_f) {
  __shared__ float4 xs[RR * DIM / 4];    // 16 KB x-tile
  __shared__ float red_v[4][RR];
  __shared__ int   red_i[4][RR];

  const int tid = threadIdx.x;
  const size_t base = (size_t)blockIdx.x * (RR * DIM);

  {
    const float4* src = (const float4*)(x + base);
    #pragma unroll
    for (int i = 0; i < 4; ++i) xs[tid + 256 * i] = src[tid + 256 * i];
  }
  __syncthreads();

  float acc[RR][4];
  #pragma unroll
  for (int r = 0; r < RR; ++r) {
    #pragma unroll
    for (int j = 0; j < 4; ++j) acc[r][j] = 0.f;
  }

  const int k0 = tid * 4;
  for (int d4 = 0; d4 < DIM / 4; ++d4) {
    const float4 e0 = *(const float4*)(emb + (size_t)(d4 * 4 + 0) * NK + k0);
    const float4 e1 = *(const float4*)(emb + (size_t)(d4 * 4 + 1) * NK + k0);
    const float4 e2 = *(const float4*)(emb + (size_t)(d4 * 4 + 2) * NK + k0);
    const float4 e3 = *(const float4*)(emb + (size_t)(d4 * 4 + 3) * NK + k0);
    #pragma unroll
    for (int r = 0; r < RR; ++r) {
      const float4 xv = xs[r * (DIM / 4) + d4];   // LDS broadcast
      acc[r][0] = fmaf(xv.x, e0.x, fmaf(xv.y, e1.x, fmaf(xv.z, e2.x, fmaf(xv.w, e3.x, acc[r][0]))));
      acc[r][1] = fmaf(xv.x, e0.y, fmaf(xv.y, e1.y, fmaf(xv.z, e2.y, fmaf(xv.w, e3.y, acc[r][1]))));
      acc[r][2] = fmaf(xv.x, e0.z, fmaf(xv.y, e1.z, fmaf(xv.z, e2.z, fmaf(xv.w, e3.z, acc[r][2]))));
      acc[r][3] = fmaf(xv.x, e0.w, fmaf(xv.y, e1.w, fmaf(xv.z, e2.w, fmaf(xv.w, e3.w, acc[r][3]))));
    }
  }

  const float4 en = *(const float4*)(enorm + k0);
  const int lane = tid & 63;
  const int wv   = tid >> 6;

  for (int r = 0; r < RR; ++r) {
    // dist = |e|^2 - 2 x.e  (row-constant |x|^2 dropped; argmin unchanged)
    float bv = en.x - 2.f * acc[r][0];
    int   bi = k0;
    { float v = en.y - 2.f * acc[r][1]; if (v < bv) { bv = v; bi = k0 + 1; } }
    { float v = en.z - 2.f * acc[r][2]; if (v < bv) { bv = v; bi = k0 + 2; } }
    { float v = en.w - 2.f * acc[r][3]; if (v < bv) { bv = v; bi = k0 + 3; } }
    // 64-lane (val,idx) min-reduce, lowest index wins ties
    for (int off = 32; off > 0; off >>= 1) {
      float ov = __shfl_xor(bv, off);
      int   oi = __shfl_xor(bi, off);
      if (ov < bv || (ov == bv && oi < bi)) { bv = ov; bi = oi; }
    }
    if (lane == 0) { red_v[wv][r] = bv; red_i[wv][r] = bi; }
  }
  __syncthreads();

  if (tid < RR) {
    float bv = red_v[0][tid];
    int   bi = red_i[0][tid];
    #pragma unroll
    for (int w = 1; w < 4; ++w) {
      float v = red_v[w][tid]; int i2 = red_i[w][tid];
      if (v < bv || (v == bv && i2 < bi)) { bv = v; bi = i2; }
    }
    const int n = blockIdx.x * RR + tid;
    idx_out[n]   = bi;
    idx_out_f[n] = (float)bi;
  }
}

// ---------------------------------------------------------------- gather + loss partials
// Block: 256 threads x 8 elems = 2048 elems (8 rows).
__global__ __launch_bounds__(256) void gather_loss_kernel(
    const float* __restrict__ x, const float* __restrict__ emb,
    const int* __restrict__ idx, float* __restrict__ out_q,
    float* __restrict__ partial) {
  const int tid = threadIdx.x;
  const size_t base = (size_t)blockIdx.x * 2048;
  float local = 0.f;
  #pragma unroll
  for (int h = 0; h < 2; ++h) {
    const size_t g = base + (size_t)h * 1024 + (size_t)tid * 4;
    const int n = (int)(g >> 8);
    const int d = (int)(g & 255);
    const int k = idx[n];
    const float* ep = emb + (size_t)d * NK + k;
    float4 q;
    q.x = ep[0]; q.y = ep[NK]; q.z = ep[2 * NK]; q.w = ep[3 * NK];
    const float4 xv = *(const float4*)(x + g);
    *(float4*)(out_q + g) = q;
    const float dx = q.x - xv.x, dy = q.y - xv.y, dz = q.z - xv.z, dw = q.w - xv.w;
    local = fmaf(dx, dx, local);
    local = fmaf(dy, dy, local);
    local = fmaf(dz, dz, local);
    local = fmaf(dw, dw, local);
  }
  for (int off = 32; off > 0; off >>= 1) local += __shfl_down(local, off);
  __shared__ float wsum[4];
  if ((tid & 63) == 0) wsum[tid >> 6] = local;
  __syncthreads();
  if (tid == 0) partial[blockIdx.x] = (wsum[0] + wsum[1]) + (wsum[2] + wsum[3]);
}

// ---------------------------------------------------------------- finalize scalars
__global__ __launch_bounds__(1024) void finalize_kernel(
    const float* __restrict__ partial, int np,
    const float* __restrict__ cs, float* __restrict__ out_s,
    float inv_count) {
  __shared__ float sd[1024];
  const int tid = threadIdx.x;

  // 1) total squared diff
  float s = 0.f;
  for (int i = tid; i < np; i += 1024) s += partial[i];
  sd[tid] = s; __syncthreads();
  for (int st = 512; st > 0; st >>= 1) {
    if (tid < st) sd[tid] += sd[tid + st];
    __syncthreads();
  }
  const float total_sq = sd[0];
  __syncthreads();

  // 2) cluster_size sum
  const float c = cs[tid];
  sd[tid] = c; __syncthreads();
  for (int st = 512; st > 0; st >>= 1) {
    if (tid < st) sd[tid] += sd[tid + st];
    __syncthreads();
  }
  const float S = sd[0];
  __syncthreads();

  // 3) entropy term
  const float p = c / (S + 1e-5f);
  sd[tid] = p * logf(p + 1e-5f);
  __syncthreads();
  for (int st = 512; st > 0; st >>= 1) {
    if (tid < st) sd[tid] += sd[tid + st];
    __syncthreads();
  }
  const float T = sd[0];
  __syncthreads();

  // 4) used codes
  sd[tid] = (c > 1e-5f) ? 1.f : 0.f;
  __syncthreads();
  for (int st = 512; st > 0; st >>= 1) {
    if (tid < st) sd[tid] += sd[tid + st];
    __syncthreads();
  }
  const float U = sd[0];

  if (tid == 0) {
    out_s[0] = 1.25f * total_sq * inv_count;  // e_latent + 0.25*q_latent (equal in value)
    out_s[1] = expf(-T);                      // perplexity
    out_s[2] = U * (1.f / 1024.f);            // code usage rate
  }
}

// ---------------------------------------------------------------- launch
extern "C" void kernel_launch(void* const* d_in, const int* in_sizes, int n_in,
                              void* d_out, int out_size, void* d_ws, size_t ws_size,
                              hipStream_t stream) {
  const float* x   = (const float*)d_in[0];
  const float* emb = (const float*)d_in[1];
  const float* cs  = (const float*)d_in[2];
  float* out = (float*)d_out;

  const int N = in_sizes[0] / DIM;          // 32768
  const size_t ND = (size_t)N * DIM;        // 8388608

  // workspace layout
  float* enorm   = (float*)d_ws;                                           // 4 KB
  int*   idxw    = (int*)((char*)d_ws + NK * sizeof(float));               // 128 KB
  float* partial = (float*)((char*)d_ws + NK * sizeof(float) + (size_t)N * sizeof(int)); // 16 KB

  const int nGather = (int)(ND / 2048);     // 4096

  enorm_kernel<<<NK / 256, 256, 0, stream>>>(emb, enorm);
  argmin_kernel<<<N / RR, 256, 0, stream>>>(x, emb, enorm, idxw, out + ND + 3);
  gather_loss_kernel<<<nGather, 256, 0, stream>>>(x, emb, idxw, out, partial);
  finalize_kernel<<<1, 1024, 0, stream>>>(partial, nGather, cs, out + ND,
                                          1.0f / (float)ND);
}